// Round 9
// baseline (816.985 us; speedup 1.0000x reference)
//
#include <hip/hip_runtime.h>
#include <cfloat>
#include <stdint.h>

// Problem dims (fixed): z_e [32,64,64,64] NCHW fp32, embedding [1024,64] fp32
// Flat rows n = b*4096 + h*64 + w  (N = 131072, D = 64, K = 1024)
// Out layout (concat, fp32): [0]=vq_loss, [1..8388608]=z_q NCHW,
//                            [8388609]=perplexity, [8388610..]=encodings [N,1024]
// ws: [0]=loss accum, [1..1024]=counts (int), [1025..2048]=e2
//
// R9: vq_main = pure compute (no streaming stores in the barriered k-loop —
// R8's per-nt barrier dragged a vmcnt(0) drain of the enc-zero burst, ~64x).
// All 571MB of output streaming lives in barrier-free vq_out. Loss comes from
// the winning distance (dist = x2+e2-2ip == sum((e-x)^2) to ~1e-5/row).

typedef __attribute__((ext_vector_type(8))) short bf8v;
typedef __attribute__((ext_vector_type(4))) float f4v;

__device__ __forceinline__ unsigned short f2bf(float v) {  // RNE
  unsigned u = __float_as_uint(v);
  return (unsigned short)((u + 0x7FFFu + ((u >> 16) & 1u)) >> 16);
}
__device__ __forceinline__ float bf2f(unsigned short h) {
  return __uint_as_float(((unsigned)h) << 16);
}

__global__ __launch_bounds__(256) void vq_prep(const float* __restrict__ emb,
                                               float* __restrict__ ws) {
  #pragma clang fp contract(off)
  int gid = blockIdx.x * 256 + threadIdx.x;   // 0..1023
  if (gid == 0) ws[0] = 0.0f;
  ((int*)ws)[1 + gid] = 0;
  const float* e = emb + (gid << 6);
  float r[8];
  #pragma unroll
  for (int j = 0; j < 8; ++j) r[j] = e[j] * e[j];
  #pragma unroll
  for (int i = 8; i < 64; i += 8) {
    #pragma unroll
    for (int j = 0; j < 8; ++j) { float s = e[i + j] * e[i + j]; r[j] = r[j] + s; }
  }
  ws[1025 + gid] = ((r[0] + r[1]) + (r[2] + r[3])) + ((r[4] + r[5]) + (r[6] + r[7]));
}

// B-fragment table in the z_q region (consumed by vq_main, overwritten later
// by vq_out): entry e = ((nt*2+kk)*3+term)*64 + lane; 16B per entry.
__global__ __launch_bounds__(256) void vq_prep_frags(const float* __restrict__ emb,
                                                     float* __restrict__ out) {
  int e = blockIdx.x * 256 + threadIdx.x;     // 0..24575
  int lane = e & 63, sub = e >> 6;
  int term = sub % 3, kk = (sub / 3) & 1, nt = sub / 6;
  int code = nt * 16 + (lane & 15);
  int d0 = kk * 32 + (lane >> 4) * 8;
  const float* src = emb + code * 64 + d0;
  unsigned short hs[8];
  #pragma unroll
  for (int j = 0; j < 8; ++j) {
    float v = src[j];
    unsigned short h = f2bf(v);  float r1 = v - bf2f(h);   // exact residual
    unsigned short m = f2bf(r1); float r2 = r1 - bf2f(m);  // exact residual
    unsigned short l = f2bf(r2);
    hs[j] = (term == 0) ? h : (term == 1) ? m : l;
  }
  uint4 p;
  p.x = (unsigned)hs[0] | ((unsigned)hs[1] << 16);
  p.y = (unsigned)hs[2] | ((unsigned)hs[3] << 16);
  p.z = (unsigned)hs[4] | ((unsigned)hs[5] << 16);
  p.w = (unsigned)hs[6] | ((unsigned)hs[7] << 16);
  ((uint4*)(out + 4))[e] = p;   // out+4 floats = +16B -> 16B aligned
}

__global__ __launch_bounds__(256, 4) void vq_main(const float* __restrict__ ze,
                                                  float* __restrict__ ws,
                                                  float* __restrict__ out) {
  __shared__ float xtile[64 * 68];                      // padded x tile
  __shared__ __align__(16) short bbuf[2 * 6 * 64 * 8];  // B-frag dbuf (12 KB)
  __shared__ float e2s[1024];
  __shared__ float x2s[64];
  __shared__ float sx[256];

  int t = threadIdx.x;
  int w = __builtin_amdgcn_readfirstlane(t >> 6);  // wave id = m-tile 0..3
  int lane = t & 63;
  int g = blockIdx.x;
  int b = g >> 6, h = g & 63;
  int n0 = g << 6;

  // ---- stage x tile (row = spatial w = lane) + e2 ----
  const float* zebase = ze + ((size_t)b << 18) + (h << 6);
  #pragma unroll
  for (int i = 0; i < 16; ++i) {
    int d = w * 16 + i;
    xtile[lane * 68 + d] = zebase[d * 4096 + lane];
  }
  e2s[t] = ws[1025 + t];         e2s[256 + t] = ws[1281 + t];
  e2s[512 + t] = ws[1537 + t];   e2s[768 + t] = ws[1793 + t];
  __syncthreads();

  // ---- x2: numpy pairwise order, exactly ----
  {
    #pragma clang fp contract(off)
    const float* xr = xtile + lane * 68;
    int j0 = 2 * w, j1 = 2 * w + 1;
    float v0 = xr[j0], v1 = xr[j1];
    float ra = v0 * v0, rb = v1 * v1;
    #pragma unroll
    for (int p = 1; p < 8; ++p) {
      float s0 = xr[8 * p + j0]; s0 = s0 * s0; ra = ra + s0;
      float s1 = xr[8 * p + j1]; s1 = s1 * s1; rb = rb + s1;
    }
    sx[lane * 4 + w] = ra + rb;
  }
  __syncthreads();
  if (t < 64) x2s[t] = (sx[t * 4] + sx[t * 4 + 1]) + (sx[t * 4 + 2] + sx[t * 4 + 3]);
  __syncthreads();

  // ---- A-frags (VGPR-resident): rows w*16..w*16+15 ----
  int qd = lane >> 4, rr = lane & 15;
  const float* xr = xtile + (w * 16 + rr) * 68;
  bf8v Ah[2], Am[2], Al[2];
  #pragma unroll
  for (int kk = 0; kk < 2; ++kk) {
    #pragma unroll
    for (int j = 0; j < 8; ++j) {
      float v = xr[kk * 32 + qd * 8 + j];
      unsigned short hh = f2bf(v);  float r1 = v - bf2f(hh);
      unsigned short mm = f2bf(r1); float r2 = r1 - bf2f(mm);
      unsigned short ll = f2bf(r2);
      Ah[kk][j] = (short)hh; Am[kk][j] = (short)mm; Al[kk][j] = (short)ll;
    }
  }
  float x2v[4];
  #pragma unroll
  for (int r = 0; r < 4; ++r) x2v[r] = x2s[w * 16 + qd * 4 + r];

  const uint4* ft = (const uint4*)(out + 4);
  uint4* bput = (uint4*)bbuf;
  float* encbase = out + 8388610 + (size_t)n0 * 1024;

  // prologue: stage nt=0 frags (wave w stages f = w, w+4)
  for (int f = w; f < 6; f += 4) bput[f * 64 + lane] = ft[f * 64 + lane];
  __syncthreads();

  unsigned long long best[4] = {~0ULL, ~0ULL, ~0ULL, ~0ULL};

  #pragma unroll 1
  for (int nt = 0; nt < 64; ++nt) {
    int cur = nt & 1, nxt = cur ^ 1;
    uint4 pv0, pv1;
    if (nt < 63) {                       // issue next-tile loads early
      pv0 = ft[((nt + 1) * 6 + w) * 64 + lane];
      if (w < 2) pv1 = ft[((nt + 1) * 6 + w + 4) * 64 + lane];
    }
    float e2v = e2s[nt * 16 + (lane & 15)];
    f4v acc = {0.0f, 0.0f, 0.0f, 0.0f};
    const bf8v* bb = (const bf8v*)bbuf + cur * 6 * 64;
    #pragma unroll
    for (int kk = 0; kk < 2; ++kk) {
      bf8v Bh = bb[(kk * 3 + 0) * 64 + lane];
      bf8v Bm = bb[(kk * 3 + 1) * 64 + lane];
      bf8v Bl = bb[(kk * 3 + 2) * 64 + lane];
      acc = __builtin_amdgcn_mfma_f32_16x16x32_bf16(Ah[kk], Bh, acc, 0, 0, 0);
      acc = __builtin_amdgcn_mfma_f32_16x16x32_bf16(Ah[kk], Bm, acc, 0, 0, 0);
      acc = __builtin_amdgcn_mfma_f32_16x16x32_bf16(Am[kk], Bh, acc, 0, 0, 0);
      acc = __builtin_amdgcn_mfma_f32_16x16x32_bf16(Am[kk], Bm, acc, 0, 0, 0);
      acc = __builtin_amdgcn_mfma_f32_16x16x32_bf16(Ah[kk], Bl, acc, 0, 0, 0);
      acc = __builtin_amdgcn_mfma_f32_16x16x32_bf16(Al[kk], Bh, acc, 0, 0, 0);
    }
    unsigned code0 = (unsigned)(nt * 16 + (lane & 15));
    #pragma unroll
    for (int r = 0; r < 4; ++r) {
      float tt = x2v[r] + e2v;                 // fl(x2+e2) like numpy
      float dd = fmaf(-2.0f, acc[r], tt);      // == fl(t - fl(2ip)); 2ip exact
      unsigned long long cand =
          (((unsigned long long)__float_as_uint(dd)) << 32) | code0;
      if (cand < best[r]) best[r] = cand;      // ties -> lower code = first-index
    }
    if (nt < 63) {
      bput[(nxt * 6 + w) * 64 + lane] = pv0;
      if (w < 2) bput[(nxt * 6 + w + 4) * 64 + lane] = pv1;
    }
    __syncthreads();
  }

  // ---- per-quad cross-lane u64 argmin ----
  #pragma unroll
  for (int r = 0; r < 4; ++r) {
    unsigned long long bu = best[r];
    #pragma unroll
    for (int m = 1; m <= 8; m <<= 1) {
      unsigned long long o = __shfl_xor(bu, m, 64);
      if (o < bu) bu = o;
    }
    best[r] = bu;
  }

  // ---- epilogue: winners stash + loss (from winning dist) + histogram ----
  // dist == x2+e2-2ip ~= sum((e-x)^2) per row to ~1e-5 abs — loss tolerance
  // is ~1e-2, aggregate error ~1e-6.
  float s4 = 0.0f;
  #pragma unroll
  for (int r = 0; r < 4; ++r) s4 += __uint_as_float((unsigned)(best[r] >> 32));
  // sum across the 4 quads (each quad's 16 lanes hold identical s4)
  s4 += __shfl_xor(s4, 16, 64);
  s4 += __shfl_xor(s4, 32, 64);
  if (lane == 0) atomicAdd(ws, s4);
  if ((lane & 15) == 0) {
    #pragma unroll
    for (int r = 0; r < 4; ++r) {
      int code = (int)(best[r] & 0xFFFFFFFFu);
      ((int*)encbase)[w * 16 + qd * 4 + r] = code;   // stash at slice head
      atomicAdd((int*)ws + 1 + code, 1);
    }
  }
}

// Barrier-free streamer: all 571MB of output writes live here.
__global__ __launch_bounds__(256) void vq_out(const float* __restrict__ emb,
                                              float* __restrict__ out) {
  __shared__ int swin[64];
  int g = blockIdx.x, t = threadIdx.x;
  int b = g >> 6, h = g & 63, n0 = g << 6;
  float* enc = out + 8388610;
  float* encb = enc + (size_t)n0 * 1024;
  if (t < 64) swin[t] = ((int*)encb)[t];    // read winners stash
  __syncthreads();

  // zero the block's 256KB enc slice (coalesced 512B per wave-instr)
  const float2 z2 = make_float2(0.0f, 0.0f);
  float2* ez = (float2*)encb;
  #pragma unroll 8
  for (int i = 0; i < 256; ++i) ez[i * 256 + t] = z2;
  __syncthreads();   // drains zero stores (vmcnt(0) pre-barrier) before 1.0s

  int row = t & 63;
  int gi = swin[row];
  if (t < 64) enc[(size_t)(n0 + t) * 1024 + swin[t]] = 1.0f;

  // z_q: wave w writes d in [16w,16w+16) for all 64 rows (coalesced along row)
  const float* er = emb + gi * 64;           // per-lane gather, L2-resident
  float* qr = out + 1 + ((size_t)b << 18) + (h << 6) + row;
  #pragma unroll
  for (int i = 0; i < 16; ++i) {
    int d = (t >> 6) * 16 + i;
    qr[(size_t)d * 4096] = er[d];
  }
}

__global__ __launch_bounds__(1024) void vq_fin(const float* __restrict__ ws,
                                               float* __restrict__ out) {
  __shared__ float sm[16];
  int t = threadIdx.x;  // 0..1023 = k
  const int* counts = (const int*)ws + 1;
  float c = (float)counts[t];
  float p = c * (1.0f / 131072.0f);
  float s = p * logf(p + 1e-10f);
  #pragma unroll
  for (int off = 32; off > 0; off >>= 1) s += __shfl_down(s, off, 64);
  if ((t & 63) == 0) sm[t >> 6] = s;
  __syncthreads();
  if (t == 0) {
    float v = 0.0f;
    #pragma unroll
    for (int i = 0; i < 16; ++i) v += sm[i];
    out[8388609] = expf(-v);               // perplexity
    float m = ws[0] / 8388608.0f;          // mean (z_q - z)^2
    out[0] = 0.25f * m + m;                // commitment + e2z
  }
}

extern "C" void kernel_launch(void* const* d_in, const int* in_sizes, int n_in,
                              void* d_out, int out_size, void* d_ws, size_t ws_size,
                              hipStream_t stream) {
  const float* ze  = (const float*)d_in[0];
  const float* emb = (const float*)d_in[1];
  float* out = (float*)d_out;
  float* ws  = (float*)d_ws;   // 2049 * 4B used
  vq_prep<<<4, 256, 0, stream>>>(emb, ws);
  vq_prep_frags<<<96, 256, 0, stream>>>(emb, out);
  vq_main<<<2048, 256, 0, stream>>>(ze, ws, out);
  vq_out<<<2048, 256, 0, stream>>>(emb, out);
  vq_fin<<<1, 1024, 0, stream>>>(ws, out);
}